// Round 6
// baseline (264.636 us; speedup 1.0000x reference)
//
#include <hip/hip_runtime.h>
#include <math.h>

#define NB 16
#define IMH 288
#define IMW 384
#define NPIX (IMH*IMW)
#define TPB 256
#define PPT 8                      // points per thread
#define BPB (NPIX/(TPB*PPT))       // 54 blocks per batch
#define NBLK (NB*BPB)              // 864
#define NITER 5

// ws layout (doubles): R[16][9] | t[16][3] | acc[NITER][16][27] ; then ints cnt[NITER*16]
#define R_OFF 0
#define T_OFF (NB*9)
#define ACC_OFF (NB*12)
#define WS_DOUBLES (NB*12 + NITER*NB*27)

__global__ void init_k(double* ws) {
    int i = threadIdx.x;
    for (int k = i; k < WS_DOUBLES; k += TPB) ws[k] = 0.0;
    int* cnt = (int*)(ws + WS_DOUBLES);
    for (int k = i; k < NITER * NB; k += TPB) cnt[k] = 0;
    __syncthreads();
    if (i < NB) {
        double* R = ws + R_OFF + i * 9;
        R[0] = 1.0; R[4] = 1.0; R[8] = 1.0;
    }
}

__global__ __launch_bounds__(TPB, 4) void reduce_k(const float* __restrict__ x3d,
                                                   const float* __restrict__ conf,
                                                   const float* __restrict__ Kmat,
                                                   double* __restrict__ ws, int it) {
    const int b = blockIdx.x / BPB;
    const int chunk = blockIdx.x % BPB;

    const double* Rd = ws + R_OFF + b * 9;
    const double* td = ws + T_OFF + b * 3;
    float R[9], t[3];
    #pragma unroll
    for (int i = 0; i < 9; i++) R[i] = (float)Rd[i];
    #pragma unroll
    for (int i = 0; i < 3; i++) t[i] = (float)td[i];

    const float fx = Kmat[b*9 + 0];
    const float fy = Kmat[b*9 + 4];
    const float cx = Kmat[b*9 + 2];
    const float cy = Kmat[b*9 + 5];
    const float delta = (float)(0.1 * sqrt(((double)(IMW*IMW - 1) + (double)(IMH*IMH - 1)) / 12.0));

    float facc[27];
    #pragma unroll
    for (int i = 0; i < 27; i++) facc[i] = 0.0f;

    // 8 consecutive points per thread; all share one pixel row (n0 % 8 == 0, IMW % 8 == 0)
    const int ft = chunk * TPB + threadIdx.x;          // [0, 13824)
    const int n0 = ft * PPT;
    const int v0 = n0 / IMW;
    const float cyv = cy - (float)v0;
    const float cxu0 = cx - (float)(n0 - v0 * IMW);

    const float4* P4 = reinterpret_cast<const float4*>(x3d + (size_t)b * NPIX * 3) + (size_t)ft * 6;
    const float4 va = P4[0];
    const float4 vb = P4[1];
    const float4 vc = P4[2];
    const float4 vd = P4[3];
    const float4 ve = P4[4];
    const float4 vf = P4[5];
    const float4* W4 = reinterpret_cast<const float4*>(conf + (size_t)b * NPIX) + (size_t)ft * 2;
    const float4 w0 = W4[0];
    const float4 w1 = W4[1];

    float ppx[8] = { va.x, va.w, vb.z, vc.y, vd.x, vd.w, ve.z, vf.y };
    float ppy[8] = { va.y, vb.x, vb.w, vc.z, vd.y, ve.x, ve.w, vf.z };
    float ppz[8] = { va.z, vb.y, vc.x, vc.w, vd.z, ve.y, vf.x, vf.w };
    float pw[8]  = { w0.x, w0.y, w0.z, w0.w, w1.x, w1.y, w1.z, w1.w };

    #pragma unroll
    for (int g = 0; g < PPT; ++g) {
        float px = ppx[g], py = ppy[g], pz = ppz[g], w = pw[g];

        float Xx = fmaf(R[0], px, fmaf(R[1], py, fmaf(R[2], pz, t[0])));
        float Xy = fmaf(R[3], px, fmaf(R[4], py, fmaf(R[5], pz, t[1])));
        float Xz = fmaf(R[6], px, fmaf(R[7], py, fmaf(R[8], pz, t[2])));
        float z  = fmaxf(Xz, 0.01f);
        float iz = __builtin_amdgcn_rcpf(z);

        float Xxiz = Xx * iz, Xyiz = Xy * iz;
        float rx = fmaf(fx, Xxiz, cxu0 - (float)g);
        float ry = fmaf(fy, Xyiz, cyv);

        float wrx = w * rx, wry = w * ry;
        float q  = fmaf(wrx, wrx, wry * wry);
        float rs = __builtin_amdgcn_rsqf(fmaxf(q, 1e-16f));    // 1/max(||wr||,1e-8)
        float rob2 = fminf(1.0f, delta * rs);
        float sq = w * __builtin_amdgcn_sqrtf(rob2);           // sqrt(robust wt) into J

        float sqiz = sq * iz;
        float a  = fx * sqiz;
        float c  = fy * sqiz;
        float bb = -a * Xxiz;
        float d  = -c * Xyiz;

        float j0[6] = { a, 0.0f, bb,  bb*Xy,                 fmaf(a, Xz, -bb*Xx), -a*Xy };
        float j1[6] = { 0.0f, c,  d,  fmaf(d, Xy, -c*Xz),   -d*Xx,                 c*Xx };
        float rxs = sq * rx, rys = sq * ry;

        int k = 0;
        #pragma unroll
        for (int f = 0; f < 6; ++f) {
            #pragma unroll
            for (int gg = f; gg < 6; ++gg) {
                facc[k] += j0[f]*j0[gg] + j1[f]*j1[gg];
                k++;
            }
        }
        #pragma unroll
        for (int f = 0; f < 6; ++f)
            facc[21 + f] += j0[f]*rxs + j1[f]*rys;
    }

    // f32 wave reduce (pairwise), f64 from wave partials on
    int lane = threadIdx.x & 63;
    int wave = threadIdx.x >> 6;
    __shared__ double lds[TPB / 64][27];
    #pragma unroll
    for (int i = 0; i < 27; i++) {
        float v = facc[i];
        for (int off = 32; off > 0; off >>= 1) v += __shfl_down(v, off, 64);
        if (lane == 0) lds[wave][i] = (double)v;
    }
    __syncthreads();

    double* acc = ws + ACC_OFF + ((size_t)it * NB + b) * 27;
    if (threadIdx.x < 27) {
        double v = 0.0;
        #pragma unroll
        for (int wv = 0; wv < TPB/64; wv++) v += lds[wv][threadIdx.x];
        atomicAdd(acc + threadIdx.x, v);
    }
    // barrier drains vmcnt -> all 27 device-scope atomics of this block are
    // globally performed before thread 0 bumps the arrival counter (R3/R4-proven).
    __syncthreads();

    if (threadIdx.x == 0) {
        int* cnt = (int*)(ws + WS_DOUBLES);
        int old = atomicAdd(&cnt[it * NB + b], 1);
        if (old == BPB - 1) {
            __threadfence();   // acquire: see all blocks' acc adds

            // ---- fully-unrolled register-resident 6x6 f64 solve ----
            double A[6][6], rhs[6], inv[6];
            {
                int k = 0;
                #pragma unroll
                for (int f = 0; f < 6; f++) {
                    #pragma unroll 6
                    for (int g = f; g < 6; g++) {
                        double v = acc[k];
                        A[f][g] = v; A[g][f] = v; k++;
                    }
                }
            }
            #pragma unroll
            for (int f = 0; f < 6; f++) rhs[f] = -acc[21 + f];

            double tr = A[0][0] + A[1][1] + A[2][2] + A[3][3] + A[4][4] + A[5][5];
            double damp = 1e-4 * tr / 6.0 + 1e-6;
            #pragma unroll
            for (int f = 0; f < 6; f++) A[f][f] += damp;

            #pragma unroll
            for (int j = 0; j < 6; j++) {
                double s = A[j][j];
                #pragma unroll 6
                for (int m = 0; m < j; m++) s -= A[j][m] * A[j][m];
                double dd = sqrt(fmax(s, 1e-30));
                A[j][j] = dd;
                inv[j] = 1.0 / dd;
                #pragma unroll 6
                for (int i = j + 1; i < 6; i++) {
                    double s2 = A[i][j];
                    #pragma unroll 6
                    for (int m = 0; m < j; m++) s2 -= A[i][m] * A[j][m];
                    A[i][j] = s2 * inv[j];
                }
            }
            #pragma unroll
            for (int i = 0; i < 6; i++) {
                double s = rhs[i];
                #pragma unroll 6
                for (int m = 0; m < i; m++) s -= A[i][m] * rhs[m];
                rhs[i] = s * inv[i];
            }
            #pragma unroll
            for (int i = 5; i >= 0; i--) {
                double s = rhs[i];
                #pragma unroll 6
                for (int m = i + 1; m < 6; m++) s -= A[m][i] * rhs[m];
                rhs[i] = s * inv[i];
            }

            double* tt = ws + T_OFF + b * 3;
            tt[0] += rhs[0]; tt[1] += rhs[1]; tt[2] += rhs[2];

            double wx = rhs[3], wy = rhs[4], wz = rhs[5];
            double th = sqrt(wx*wx + wy*wy + wz*wz);
            th = fmax(th, 1e-8);
            double ith = 1.0 / th;
            double kx = wx*ith, ky = wy*ith, kz = wz*ith;
            float stf, ctf;
            sincosf((float)th, &stf, &ctf);   // f32 trig == reference semantics
            double st = (double)stf, ct = 1.0 - (double)ctf;
            double E[9];
            E[0] = 1.0 + ct*(kx*kx - 1.0);
            E[1] = -st*kz + ct*kx*ky;
            E[2] =  st*ky + ct*kx*kz;
            E[3] =  st*kz + ct*ky*kx;
            E[4] = 1.0 + ct*(ky*ky - 1.0);
            E[5] = -st*kx + ct*ky*kz;
            E[6] = -st*ky + ct*kz*kx;
            E[7] =  st*kx + ct*kz*ky;
            E[8] = 1.0 + ct*(kz*kz - 1.0);

            double* Rw = ws + R_OFF + b * 9;
            double R0 = Rw[0], R1 = Rw[1], R2 = Rw[2];
            double R3 = Rw[3], R4 = Rw[4], R5 = Rw[5];
            double R6 = Rw[6], R7 = Rw[7], R8 = Rw[8];
            Rw[0] = E[0]*R0 + E[1]*R3 + E[2]*R6;
            Rw[1] = E[0]*R1 + E[1]*R4 + E[2]*R7;
            Rw[2] = E[0]*R2 + E[1]*R5 + E[2]*R8;
            Rw[3] = E[3]*R0 + E[4]*R3 + E[5]*R6;
            Rw[4] = E[3]*R1 + E[4]*R4 + E[5]*R7;
            Rw[5] = E[3]*R2 + E[4]*R5 + E[5]*R8;
            Rw[6] = E[6]*R0 + E[7]*R3 + E[8]*R6;
            Rw[7] = E[6]*R1 + E[7]*R4 + E[8]*R7;
            Rw[8] = E[6]*R2 + E[7]*R5 + E[8]*R8;
            // pose visible to next kernel via launch boundary
        }
    }
}

__global__ __launch_bounds__(64) void loss_k(const double* __restrict__ ws,
                                             const float* __restrict__ pose,
                                             float* __restrict__ out) {
    int lane = threadIdx.x;
    double rot = 0.0, trans = 0.0;
    if (lane < NB) {
        const float* P0 = pose;
        const float* Pb = pose + lane * 16;
        double R0t[9];
        #pragma unroll
        for (int i = 0; i < 3; i++)
            #pragma unroll
            for (int j = 0; j < 3; j++) R0t[i*3+j] = (double)P0[j*4+i];
        double t0i[3];
        #pragma unroll
        for (int i = 0; i < 3; i++)
            t0i[i] = -(R0t[i*3+0]*P0[0*4+3] + R0t[i*3+1]*P0[1*4+3] + R0t[i*3+2]*P0[2*4+3]);
        double Rg[9], tg[3];
        #pragma unroll
        for (int i = 0; i < 3; i++) {
            #pragma unroll
            for (int j = 0; j < 3; j++)
                Rg[i*3+j] = R0t[i*3+0]*Pb[0*4+j] + R0t[i*3+1]*Pb[1*4+j] + R0t[i*3+2]*Pb[2*4+j];
            tg[i] = R0t[i*3+0]*Pb[0*4+3] + R0t[i*3+1]*Pb[1*4+3] + R0t[i*3+2]*Pb[2*4+3] + t0i[i];
        }
        const double* Q0  = ws + R_OFF;
        const double* q0t = ws + T_OFF;
        const double* Qb  = ws + R_OFF + lane * 9;
        const double* qbt = ws + T_OFF + lane * 3;
        double Rp0t[9];
        #pragma unroll
        for (int i = 0; i < 3; i++)
            #pragma unroll
            for (int j = 0; j < 3; j++) Rp0t[i*3+j] = Q0[j*3+i];
        double tp0i[3];
        #pragma unroll
        for (int i = 0; i < 3; i++)
            tp0i[i] = -(Rp0t[i*3+0]*q0t[0] + Rp0t[i*3+1]*q0t[1] + Rp0t[i*3+2]*q0t[2]);
        double Rp[9], tp[3];
        #pragma unroll
        for (int i = 0; i < 3; i++) {
            #pragma unroll
            for (int j = 0; j < 3; j++)
                Rp[i*3+j] = Rp0t[i*3+0]*Qb[0*3+j] + Rp0t[i*3+1]*Qb[1*3+j] + Rp0t[i*3+2]*Qb[2*3+j];
            tp[i] = Rp0t[i*3+0]*qbt[0] + Rp0t[i*3+1]*qbt[1] + Rp0t[i*3+2]*qbt[2] + tp0i[i];
        }
        double trace = 0.0;
        #pragma unroll
        for (int i = 0; i < 3; i++)
            trace += Rp[0*3+i]*Rg[0*3+i] + Rp[1*3+i]*Rg[1*3+i] + Rp[2*3+i]*Rg[2*3+i];
        double cosang = 0.5 * (trace - 1.0);
        double lo = -1.0 + 1e-7, hi = 1.0 - 1e-7;
        cosang = fmin(fmax(cosang, lo), hi);
        rot = acos(cosang);
        double d0 = tp[0]-tg[0], d1 = tp[1]-tg[1], d2 = tp[2]-tg[2];
        trans = sqrt(d0*d0 + d1*d1 + d2*d2);
    }
    for (int off = 8; off > 0; off >>= 1) {
        rot   += __shfl_down(rot, off, 64);
        trans += __shfl_down(trans, off, 64);
    }
    if (lane == 0) {
        rot /= NB; trans /= NB;
        out[0] = (float)(rot + trans);
        out[1] = (float)rot;
        out[2] = (float)trans;
    }
}

extern "C" void kernel_launch(void* const* d_in, const int* in_sizes, int n_in,
                              void* d_out, int out_size, void* d_ws, size_t ws_size,
                              hipStream_t stream) {
    const float* x3d  = (const float*)d_in[0];
    const float* conf = (const float*)d_in[1];
    const float* Kmat = (const float*)d_in[2];
    const float* pose = (const float*)d_in[3];
    float* out = (float*)d_out;
    double* ws = (double*)d_ws;

    hipLaunchKernelGGL(init_k, dim3(1), dim3(TPB), 0, stream, ws);
    for (int it = 0; it < NITER; ++it) {
        hipLaunchKernelGGL(reduce_k, dim3(NBLK), dim3(TPB), 0, stream,
                           x3d, conf, Kmat, ws, it);
    }
    hipLaunchKernelGGL(loss_k, dim3(1), dim3(64), 0, stream, ws, pose, out);
}

// Round 7
// 86.024 us; speedup vs baseline: 3.0763x; 3.0763x over previous
//
#include <hip/hip_runtime.h>
#include <math.h>

#define NB 16
#define IMH 288
#define IMW 384
#define NPIX (IMH*IMW)
#define TPB 256
#define PPT 8                      // points per thread
#define BPB (NPIX/(TPB*PPT))       // 54 blocks per batch
#define NBLK (NB*BPB)              // 864
#define NITER 5

// ws doubles layout: pose[2][NB][12] (R[9]+t[3], parity buffers) | acc[NITER][NB][27]
#define POSE_OFF 0
#define ACC_OFF (2*NB*12)
#define WS_DOUBLES (2*NB*12 + NITER*NB*27)

// Register-resident f64: pose_out = LM-update(pose_in, acc). Fully unrolled.
__device__ __forceinline__ void solve_update(const double* __restrict__ acc,
                                             const double* __restrict__ pin,
                                             double* __restrict__ Ro,
                                             double* __restrict__ to) {
    double A[6][6], rhs[6], inv[6];
    {
        int k = 0;
        #pragma unroll
        for (int f = 0; f < 6; f++) {
            #pragma unroll 6
            for (int g = f; g < 6; g++) {
                double v = acc[k];
                A[f][g] = v; A[g][f] = v; k++;
            }
        }
    }
    #pragma unroll
    for (int f = 0; f < 6; f++) rhs[f] = -acc[21 + f];

    double tr = A[0][0] + A[1][1] + A[2][2] + A[3][3] + A[4][4] + A[5][5];
    double damp = 1e-4 * tr / 6.0 + 1e-6;
    #pragma unroll
    for (int f = 0; f < 6; f++) A[f][f] += damp;

    #pragma unroll
    for (int j = 0; j < 6; j++) {
        double s = A[j][j];
        #pragma unroll 6
        for (int m = 0; m < j; m++) s -= A[j][m] * A[j][m];
        double dd = sqrt(fmax(s, 1e-30));
        A[j][j] = dd;
        inv[j] = 1.0 / dd;
        #pragma unroll 6
        for (int i = j + 1; i < 6; i++) {
            double s2 = A[i][j];
            #pragma unroll 6
            for (int m = 0; m < j; m++) s2 -= A[i][m] * A[j][m];
            A[i][j] = s2 * inv[j];
        }
    }
    #pragma unroll
    for (int i = 0; i < 6; i++) {
        double s = rhs[i];
        #pragma unroll 6
        for (int m = 0; m < i; m++) s -= A[i][m] * rhs[m];
        rhs[i] = s * inv[i];
    }
    #pragma unroll
    for (int i = 5; i >= 0; i--) {
        double s = rhs[i];
        #pragma unroll 6
        for (int m = i + 1; m < 6; m++) s -= A[m][i] * rhs[m];
        rhs[i] = s * inv[i];
    }

    to[0] = pin[9]  + rhs[0];
    to[1] = pin[10] + rhs[1];
    to[2] = pin[11] + rhs[2];

    double wx = rhs[3], wy = rhs[4], wz = rhs[5];
    double th = sqrt(wx*wx + wy*wy + wz*wz);
    th = fmax(th, 1e-8);
    double ith = 1.0 / th;
    double kx = wx*ith, ky = wy*ith, kz = wz*ith;
    float stf, ctf;
    sincosf((float)th, &stf, &ctf);      // f32 trig == reference semantics
    double st = (double)stf, ct = 1.0 - (double)ctf;
    double E[9];
    E[0] = 1.0 + ct*(kx*kx - 1.0);
    E[1] = -st*kz + ct*kx*ky;
    E[2] =  st*ky + ct*kx*kz;
    E[3] =  st*kz + ct*ky*kx;
    E[4] = 1.0 + ct*(ky*ky - 1.0);
    E[5] = -st*kx + ct*ky*kz;
    E[6] = -st*ky + ct*kz*kx;
    E[7] =  st*kx + ct*kz*ky;
    E[8] = 1.0 + ct*(kz*kz - 1.0);

    #pragma unroll
    for (int i = 0; i < 3; i++) {
        #pragma unroll
        for (int j = 0; j < 3; j++)
            Ro[i*3+j] = E[i*3+0]*pin[0*3+j] + E[i*3+1]*pin[1*3+j] + E[i*3+2]*pin[2*3+j];
    }
}

__global__ void init_k(double* ws) {
    int i = threadIdx.x;
    for (int k = i; k < WS_DOUBLES; k += TPB) ws[k] = 0.0;
    __syncthreads();
    if (i < NB) {
        double* p = ws + POSE_OFF + i * 12;   // parity buffer 0 = identity
        p[0] = 1.0; p[4] = 1.0; p[8] = 1.0;
    }
}

__global__ __launch_bounds__(TPB) void reduce_k(const float* __restrict__ x3d,
                                                const float* __restrict__ conf,
                                                const float* __restrict__ Kmat,
                                                double* __restrict__ ws, int it) {
    const int b = blockIdx.x / BPB;
    const int chunk = blockIdx.x % BPB;

    __shared__ double sp[12];
    __shared__ double lds[TPB / 64][27];

    float R[9], t[3];
    if (it == 0) {
        R[0]=1.f; R[1]=0.f; R[2]=0.f;
        R[3]=0.f; R[4]=1.f; R[5]=0.f;
        R[6]=0.f; R[7]=0.f; R[8]=1.f;
        t[0]=t[1]=t[2]=0.f;
    } else {
        // wave 0 redundantly computes pose_it from pose_{it-1} + acc_{it-1}
        if ((threadIdx.x >> 6) == 0) {
            const double* accp = ws + ACC_OFF + ((size_t)(it-1) * NB + b) * 27;
            const double* pin  = ws + POSE_OFF + (size_t)((it-1) & 1) * NB * 12 + b * 12;
            double Rn[9], tn[3];
            solve_update(accp, pin, Rn, tn);
            if (threadIdx.x == 0) {
                #pragma unroll
                for (int i = 0; i < 9; i++) sp[i] = Rn[i];
                sp[9] = tn[0]; sp[10] = tn[1]; sp[11] = tn[2];
                if (chunk == 0) {   // single writer publishes pose_it (read next dispatch)
                    double* pout = ws + POSE_OFF + (size_t)(it & 1) * NB * 12 + b * 12;
                    #pragma unroll
                    for (int i = 0; i < 9; i++) pout[i] = Rn[i];
                    pout[9] = tn[0]; pout[10] = tn[1]; pout[11] = tn[2];
                }
            }
        }
        __syncthreads();
        #pragma unroll
        for (int i = 0; i < 9; i++) R[i] = (float)sp[i];
        t[0] = (float)sp[9]; t[1] = (float)sp[10]; t[2] = (float)sp[11];
    }

    const float fx = Kmat[b*9 + 0];
    const float fy = Kmat[b*9 + 4];
    const float cx = Kmat[b*9 + 2];
    const float cy = Kmat[b*9 + 5];
    const float delta = (float)(0.1 * sqrt(((double)(IMW*IMW - 1) + (double)(IMH*IMH - 1)) / 12.0));

    float facc[27];
    #pragma unroll
    for (int i = 0; i < 27; i++) facc[i] = 0.0f;

    // 8 consecutive points/thread, same pixel row (n0%8==0, IMW%8==0)
    const int ft = chunk * TPB + threadIdx.x;          // [0, 13824)
    const int n0 = ft * PPT;
    const int v0 = n0 / IMW;
    const float cyv  = cy - (float)v0;
    const float cxu0 = cx - (float)(n0 - v0 * IMW);

    const float4* P4 = reinterpret_cast<const float4*>(x3d + (size_t)b * NPIX * 3) + (size_t)ft * 6;
    const float4* W4 = reinterpret_cast<const float4*>(conf + (size_t)b * NPIX) + (size_t)ft * 2;

    // two groups of 4 points: halves live registers vs 8-wide staging
    #pragma unroll
    for (int grp = 0; grp < 2; ++grp) {
        const float4 va = P4[grp*3 + 0];
        const float4 vb = P4[grp*3 + 1];
        const float4 vc = P4[grp*3 + 2];
        const float4 vw = W4[grp];
        float ppx[4] = { va.x, va.w, vb.z, vc.y };
        float ppy[4] = { va.y, vb.x, vb.w, vc.z };
        float ppz[4] = { va.z, vb.y, vc.x, vc.w };
        float pw[4]  = { vw.x, vw.y, vw.z, vw.w };

        #pragma unroll
        for (int g = 0; g < 4; ++g) {
            float px = ppx[g], py = ppy[g], pz = ppz[g], w = pw[g];
            float u_off = cxu0 - (float)(grp * 4 + g);

            float Xx = fmaf(R[0], px, fmaf(R[1], py, fmaf(R[2], pz, t[0])));
            float Xy = fmaf(R[3], px, fmaf(R[4], py, fmaf(R[5], pz, t[1])));
            float Xz = fmaf(R[6], px, fmaf(R[7], py, fmaf(R[8], pz, t[2])));
            float z  = fmaxf(Xz, 0.01f);
            float iz = __builtin_amdgcn_rcpf(z);

            float Xxiz = Xx * iz, Xyiz = Xy * iz;
            float rx = fmaf(fx, Xxiz, u_off);
            float ry = fmaf(fy, Xyiz, cyv);

            float wrx = w * rx, wry = w * ry;
            float q  = fmaf(wrx, wrx, wry * wry);
            float rs = __builtin_amdgcn_rsqf(fmaxf(q, 1e-16f));
            float rob2 = fminf(1.0f, delta * rs);
            float sq = w * __builtin_amdgcn_sqrtf(rob2);

            float sqiz = sq * iz;
            float a  = fx * sqiz;
            float c  = fy * sqiz;
            float bb = -a * Xxiz;
            float d  = -c * Xyiz;

            float j0[6] = { a, 0.0f, bb,  bb*Xy,               fmaf(a, Xz, -bb*Xx), -a*Xy };
            float j1[6] = { 0.0f, c,  d,  fmaf(d, Xy, -c*Xz), -d*Xx,                 c*Xx };
            float rxs = sq * rx, rys = sq * ry;

            int k = 0;
            #pragma unroll
            for (int f = 0; f < 6; ++f) {
                #pragma unroll
                for (int gg = f; gg < 6; ++gg) {
                    facc[k] += j0[f]*j0[gg] + j1[f]*j1[gg];
                    k++;
                }
            }
            #pragma unroll
            for (int f = 0; f < 6; ++f)
                facc[21 + f] += j0[f]*rxs + j1[f]*rys;
        }
    }

    // f32 wave reduce (pairwise), f64 from wave partials on
    int lane = threadIdx.x & 63;
    int wave = threadIdx.x >> 6;
    #pragma unroll
    for (int i = 0; i < 27; i++) {
        float v = facc[i];
        for (int off = 32; off > 0; off >>= 1) v += __shfl_down(v, off, 64);
        if (lane == 0) lds[wave][i] = (double)v;
    }
    __syncthreads();

    double* acc = ws + ACC_OFF + ((size_t)it * NB + b) * 27;
    if (threadIdx.x < 27) {
        double v = 0.0;
        #pragma unroll
        for (int wv = 0; wv < TPB/64; wv++) v += lds[wv][threadIdx.x];
        atomicAdd(acc + threadIdx.x, v);
    }
}

__global__ __launch_bounds__(64) void loss_k(const double* __restrict__ ws,
                                             const float* __restrict__ pose,
                                             float* __restrict__ out) {
    int lane = threadIdx.x;
    double Rp[9] = {1,0,0, 0,1,0, 0,0,1}, tp[3] = {0,0,0};
    if (lane < NB) {
        const double* accp = ws + ACC_OFF + ((size_t)(NITER-1) * NB + lane) * 27;
        const double* pin  = ws + POSE_OFF + (size_t)((NITER-1) & 1) * NB * 12 + lane * 12;
        solve_update(accp, pin, Rp, tp);
    }
    // broadcast batch-0 predicted pose to all lanes
    double Rp0[9], tp0v[3];
    #pragma unroll
    for (int i = 0; i < 9; i++) Rp0[i] = __shfl(Rp[i], 0, 64);
    #pragma unroll
    for (int i = 0; i < 3; i++) tp0v[i] = __shfl(tp[i], 0, 64);

    double rot = 0.0, trans = 0.0;
    if (lane < NB) {
        // gt_rel = inv(P0) @ Pb
        const float* P0 = pose;
        const float* Pb = pose + lane * 16;
        double R0t[9];
        #pragma unroll
        for (int i = 0; i < 3; i++)
            #pragma unroll
            for (int j = 0; j < 3; j++) R0t[i*3+j] = (double)P0[j*4+i];
        double t0i[3];
        #pragma unroll
        for (int i = 0; i < 3; i++)
            t0i[i] = -(R0t[i*3+0]*P0[0*4+3] + R0t[i*3+1]*P0[1*4+3] + R0t[i*3+2]*P0[2*4+3]);
        double Rg[9], tg[3];
        #pragma unroll
        for (int i = 0; i < 3; i++) {
            #pragma unroll
            for (int j = 0; j < 3; j++)
                Rg[i*3+j] = R0t[i*3+0]*Pb[0*4+j] + R0t[i*3+1]*Pb[1*4+j] + R0t[i*3+2]*Pb[2*4+j];
            tg[i] = R0t[i*3+0]*Pb[0*4+3] + R0t[i*3+1]*Pb[1*4+3] + R0t[i*3+2]*Pb[2*4+3] + t0i[i];
        }
        // pred_rel = inv(T0) @ Tb   (T0 from lane 0 broadcast)
        double Rp0t[9];
        #pragma unroll
        for (int i = 0; i < 3; i++)
            #pragma unroll
            for (int j = 0; j < 3; j++) Rp0t[i*3+j] = Rp0[j*3+i];
        double tp0i[3];
        #pragma unroll
        for (int i = 0; i < 3; i++)
            tp0i[i] = -(Rp0t[i*3+0]*tp0v[0] + Rp0t[i*3+1]*tp0v[1] + Rp0t[i*3+2]*tp0v[2]);
        double Rr[9], tr[3];
        #pragma unroll
        for (int i = 0; i < 3; i++) {
            #pragma unroll
            for (int j = 0; j < 3; j++)
                Rr[i*3+j] = Rp0t[i*3+0]*Rp[0*3+j] + Rp0t[i*3+1]*Rp[1*3+j] + Rp0t[i*3+2]*Rp[2*3+j];
            tr[i] = Rp0t[i*3+0]*tp[0] + Rp0t[i*3+1]*tp[1] + Rp0t[i*3+2]*tp[2] + tp0i[i];
        }
        double trace = 0.0;
        #pragma unroll
        for (int i = 0; i < 3; i++)
            trace += Rr[0*3+i]*Rg[0*3+i] + Rr[1*3+i]*Rg[1*3+i] + Rr[2*3+i]*Rg[2*3+i];
        double cosang = 0.5 * (trace - 1.0);
        double lo = -1.0 + 1e-7, hi = 1.0 - 1e-7;
        cosang = fmin(fmax(cosang, lo), hi);
        rot = acos(cosang);
        double d0 = tr[0]-tg[0], d1 = tr[1]-tg[1], d2 = tr[2]-tg[2];
        trans = sqrt(d0*d0 + d1*d1 + d2*d2);
    }
    for (int off = 8; off > 0; off >>= 1) {
        rot   += __shfl_down(rot, off, 64);
        trans += __shfl_down(trans, off, 64);
    }
    if (lane == 0) {
        rot /= NB; trans /= NB;
        out[0] = (float)(rot + trans);
        out[1] = (float)rot;
        out[2] = (float)trans;
    }
}

extern "C" void kernel_launch(void* const* d_in, const int* in_sizes, int n_in,
                              void* d_out, int out_size, void* d_ws, size_t ws_size,
                              hipStream_t stream) {
    const float* x3d  = (const float*)d_in[0];
    const float* conf = (const float*)d_in[1];
    const float* Kmat = (const float*)d_in[2];
    const float* pose = (const float*)d_in[3];
    float* out = (float*)d_out;
    double* ws = (double*)d_ws;

    hipLaunchKernelGGL(init_k, dim3(1), dim3(TPB), 0, stream, ws);
    for (int it = 0; it < NITER; ++it) {
        hipLaunchKernelGGL(reduce_k, dim3(NBLK), dim3(TPB), 0, stream,
                           x3d, conf, Kmat, ws, it);
    }
    hipLaunchKernelGGL(loss_k, dim3(1), dim3(64), 0, stream, ws, pose, out);
}